// Round 1
// baseline (172.223 us; speedup 1.0000x reference)
//
#include <hip/hip_runtime.h>
#include <math.h>

#define C_CH 256
#define HW 128
#define T 32           // output tile
#define YT (T + 4)     // y tile with halo 2 = 36
#define XT (T + 2)     // x_stage / f_gate tile with halo 1 = 34

__global__ __launch_bounds__(256) void fused_gated_dwconv(
    const float* __restrict__ x, const float* __restrict__ y,
    const float* __restrict__ w, const float* __restrict__ b,
    float* __restrict__ out)
{
    const int plane = blockIdx.z;            // b*C + c
    const int c     = plane & (C_CH - 1);
    const int tile_y = blockIdx.y * T;
    const int tile_x = blockIdx.x * T;

    const size_t poff = (size_t)plane * (HW * HW);
    const float* yp = y + poff;
    const float* xp = x + poff;
    float*       op = out + poff;

    float wk[9];
#pragma unroll
    for (int k = 0; k < 9; ++k) wk[k] = w[c * 9 + k];
    const float bias = b[c];

    __shared__ float ysm[YT][YT + 1];    // y with halo 2
    __shared__ float xssm[XT][XT + 1];   // x_stage with halo 1
    __shared__ float fgsm[XT][XT + 1];   // f_gate with halo 1

    const int tid = threadIdx.x;

    // ---- Stage 1: load y tile (halo 2), zero-padded at image borders ----
    for (int i = tid; i < YT * YT; i += 256) {
        int r = i / YT, cc = i - r * YT;
        int gy = tile_y + r - 2, gx = tile_x + cc - 2;
        float v = 0.f;
        if ((unsigned)gy < HW && (unsigned)gx < HW) v = yp[gy * HW + gx];
        ysm[r][cc] = v;
    }
    __syncthreads();

    // ---- Stage 2: f_feat = conv(y) over halo-1 region; x_stage, f_gate ----
    for (int i = tid; i < XT * XT; i += 256) {
        int r = i / XT, cc = i - r * XT;
        // halo-1 pixel (r,cc) is global (tile_y + r - 1, tile_x + cc - 1)
        // its conv window in ysm starts at [r][cc]
        float s = bias;
#pragma unroll
        for (int dy = 0; dy < 3; ++dy)
#pragma unroll
            for (int dx = 0; dx < 3; ++dx)
                s = fmaf(wk[dy * 3 + dx], ysm[r + dy][cc + dx], s);
        float fg = 1.f / (1.f + __expf(-s));
        float th = tanhf(s);
        int gy = tile_y + r - 1, gx = tile_x + cc - 1;
        float xs = 0.f;  // reference zero-pads x_stage outside the image
        if ((unsigned)gy < HW && (unsigned)gx < HW) {
            float xv = xp[gy * HW + gx];
            xs = fmaf(xv, fg, fg * th);   // x*f_gate + f_gate*tanh(f_feat)
        }
        xssm[r][cc] = xs;
        fgsm[r][cc] = fg;
    }
    __syncthreads();

    // ---- Stage 3: conv(x_stage) at center; out = tanh(.)*f_gate + 2y ----
    for (int i = tid; i < T * T; i += 256) {
        int r = i / T, cc = i - r * T;
        float s = bias;
#pragma unroll
        for (int dy = 0; dy < 3; ++dy)
#pragma unroll
            for (int dx = 0; dx < 3; ++dx)
                s = fmaf(wk[dy * 3 + dx], xssm[r + dy][cc + dx], s);
        int gy = tile_y + r, gx = tile_x + cc;
        float yv = ysm[r + 2][cc + 2];
        op[gy * HW + gx] = fmaf(tanhf(s), fgsm[r + 1][cc + 1], 2.f * yv);
    }
}

extern "C" void kernel_launch(void* const* d_in, const int* in_sizes, int n_in,
                              void* d_out, int out_size, void* d_ws, size_t ws_size,
                              hipStream_t stream) {
    const float* x  = (const float*)d_in[0];
    const float* y  = (const float*)d_in[1];
    const float* w  = (const float*)d_in[2];
    const float* b  = (const float*)d_in[3];
    float* out = (float*)d_out;

    const int planes = in_sizes[0] / (HW * HW);   // B*C = 2048
    dim3 grid(HW / T, HW / T, planes);            // 4 x 4 x 2048
    dim3 block(256);
    fused_gated_dwconv<<<grid, block, 0, stream>>>(x, y, w, b, out);
}

// Round 2
// 114.188 us; speedup vs baseline: 1.5082x; 1.5082x over previous
//
#include <hip/hip_runtime.h>
#include <hip/hip_fp16.h>
#include <math.h>

#define HW   128
#define TH   32          // rows per tile (tile = 128 wide x 32 tall)
#define C_CH 256
#define YROWS (TH + 4)   // 36 rows of y (halo 2)
#define XROWS (TH + 2)   // 34 rows of x_stage (halo 1)
#define LDW  136         // LDS row stride in floats (4 pad + 128 + 4 pad)
#define P    4           // left pad

__device__ __forceinline__ void sig_tanh(float s, float& fg, float& th) {
    float sc = fminf(15.f, fmaxf(-15.f, s));
    float t  = __expf(-sc);                       // e^-s
    fg = __builtin_amdgcn_rcpf(1.f + t);          // sigmoid
    float t2 = t * t;                             // e^-2s
    th = (1.f - t2) * __builtin_amdgcn_rcpf(1.f + t2);  // tanh
}

__device__ __forceinline__ float tanh_fast(float s) {
    float sc = fminf(15.f, fmaxf(-15.f, s));
    float t2 = __expf(-2.f * sc);
    return (1.f - t2) * __builtin_amdgcn_rcpf(1.f + t2);
}

__global__ __launch_bounds__(256) void fused_gated_dwconv(
    const float* __restrict__ x, const float* __restrict__ y,
    const float* __restrict__ w, const float* __restrict__ b,
    float* __restrict__ out)
{
    __shared__ __align__(16) float ysm[YROWS][LDW];
    __shared__ __align__(16) float xssm[XROWS][LDW];
    __shared__ uint32_t fgsm[TH][HW / 2];   // f_gate packed half2

    const int ty    = blockIdx.x * TH;      // 0,32,64,96
    const int plane = blockIdx.y;           // b*C + c
    const int c     = plane & (C_CH - 1);
    const size_t poff = (size_t)plane * (HW * HW);
    const float* yp = y + poff;
    const float* xp = x + poff;
    float*       op = out + poff;

    float wk[9];
#pragma unroll
    for (int k = 0; k < 9; ++k) wk[k] = w[c * 9 + k];
    const float bias = b[c];

    const int tid = threadIdx.x;

    // zero the pad columns actually read: col idx 3 (= img col -1) and 132 (= img col 128)
    for (int i = tid; i < (YROWS + XROWS) * 2; i += 256) {
        int rr = i >> 1;
        int col = (i & 1) ? (P + HW) : (P - 1);
        if (rr < YROWS) ysm[rr][col] = 0.f;
        else            xssm[rr - YROWS][col] = 0.f;
    }

    // ---- Stage 1: load y tile, 36 rows x 32 float4, zero-padded rows ----
    for (int i = tid; i < YROWS * (HW / 4); i += 256) {
        int r = i >> 5, k = i & 31;
        int gy = ty + r - 2;
        float4 v = make_float4(0.f, 0.f, 0.f, 0.f);
        if ((unsigned)gy < HW)
            v = *reinterpret_cast<const float4*>(yp + gy * HW + k * 4);
        *reinterpret_cast<float4*>(&ysm[r][P + k * 4]) = v;
    }
    __syncthreads();

    // ---- Stage 2: f_feat = conv(y); x_stage = fg*(x + tanh(f_feat)) ----
    for (int i = tid; i < XROWS * (HW / 4); i += 256) {
        int q = i >> 5, k = i & 31;
        int c0 = k * 4;
        int gy = ty + q - 1;
        bool inimg = (unsigned)gy < HW;

        float4 xv = make_float4(0.f, 0.f, 0.f, 0.f);
        if (inimg)   // issue global load early; overlaps LDS reads + FMAs below
            xv = *reinterpret_cast<const float4*>(xp + gy * HW + c0);

        float4 s = make_float4(bias, bias, bias, bias);
#pragma unroll
        for (int dy = 0; dy < 3; ++dy) {
            const float* row = &ysm[q + dy][P + c0];
            float4 f4 = *reinterpret_cast<const float4*>(row);
            float sl = row[-1], sr = row[4];
            float w0 = wk[dy * 3], w1 = wk[dy * 3 + 1], w2 = wk[dy * 3 + 2];
            s.x = fmaf(w0, sl,   fmaf(w1, f4.x, fmaf(w2, f4.y, s.x)));
            s.y = fmaf(w0, f4.x, fmaf(w1, f4.y, fmaf(w2, f4.z, s.y)));
            s.z = fmaf(w0, f4.y, fmaf(w1, f4.z, fmaf(w2, f4.w, s.z)));
            s.w = fmaf(w0, f4.z, fmaf(w1, f4.w, fmaf(w2, sr,   s.w)));
        }

        float4 xs = make_float4(0.f, 0.f, 0.f, 0.f);
        if (inimg) {
            float fg0, fg1, fg2, fg3, th0, th1, th2, th3;
            sig_tanh(s.x, fg0, th0);
            sig_tanh(s.y, fg1, th1);
            sig_tanh(s.z, fg2, th2);
            sig_tanh(s.w, fg3, th3);
            xs.x = fg0 * (xv.x + th0);
            xs.y = fg1 * (xv.y + th1);
            xs.z = fg2 * (xv.z + th2);
            xs.w = fg3 * (xv.w + th3);
            if (q >= 1 && q <= TH) {   // center rows: stash f_gate as half2
                __half2 h01 = __floats2half2_rn(fg0, fg1);
                __half2 h23 = __floats2half2_rn(fg2, fg3);
                fgsm[q - 1][k * 2]     = *reinterpret_cast<uint32_t*>(&h01);
                fgsm[q - 1][k * 2 + 1] = *reinterpret_cast<uint32_t*>(&h23);
            }
        }
        *reinterpret_cast<float4*>(&xssm[q][P + c0]) = xs;
    }
    __syncthreads();

    // ---- Stage 3: out = tanh(conv(x_stage))*f_gate + 2y ----
    for (int i = tid; i < TH * (HW / 4); i += 256) {
        int r = i >> 5, k = i & 31;
        int c0 = k * 4;

        float4 s = make_float4(bias, bias, bias, bias);
#pragma unroll
        for (int dy = 0; dy < 3; ++dy) {
            const float* row = &xssm[r + dy][P + c0];
            float4 f4 = *reinterpret_cast<const float4*>(row);
            float sl = row[-1], sr = row[4];
            float w0 = wk[dy * 3], w1 = wk[dy * 3 + 1], w2 = wk[dy * 3 + 2];
            s.x = fmaf(w0, sl,   fmaf(w1, f4.x, fmaf(w2, f4.y, s.x)));
            s.y = fmaf(w0, f4.x, fmaf(w1, f4.y, fmaf(w2, f4.z, s.y)));
            s.z = fmaf(w0, f4.y, fmaf(w1, f4.z, fmaf(w2, f4.w, s.z)));
            s.w = fmaf(w0, f4.z, fmaf(w1, f4.w, fmaf(w2, sr,   s.w)));
        }

        uint32_t u01 = fgsm[r][k * 2], u23 = fgsm[r][k * 2 + 1];
        float2 fg01 = __half22float2(*reinterpret_cast<__half2*>(&u01));
        float2 fg23 = __half22float2(*reinterpret_cast<__half2*>(&u23));
        float4 yv = *reinterpret_cast<const float4*>(&ysm[r + 2][P + c0]);

        float4 o;
        o.x = fmaf(tanh_fast(s.x), fg01.x, 2.f * yv.x);
        o.y = fmaf(tanh_fast(s.y), fg01.y, 2.f * yv.y);
        o.z = fmaf(tanh_fast(s.z), fg23.x, 2.f * yv.z);
        o.w = fmaf(tanh_fast(s.w), fg23.y, 2.f * yv.w);

        int gy = ty + r;
        *reinterpret_cast<float4*>(op + gy * HW + c0) = o;
    }
}

extern "C" void kernel_launch(void* const* d_in, const int* in_sizes, int n_in,
                              void* d_out, int out_size, void* d_ws, size_t ws_size,
                              hipStream_t stream) {
    const float* x = (const float*)d_in[0];
    const float* y = (const float*)d_in[1];
    const float* w = (const float*)d_in[2];
    const float* b = (const float*)d_in[3];
    float* out = (float*)d_out;

    const int planes = in_sizes[0] / (HW * HW);   // B*C = 2048
    dim3 grid(HW / TH, planes);                   // 4 x 2048
    dim3 block(256);
    fused_gated_dwconv<<<grid, block, 0, stream>>>(x, y, w, b, out);
}

// Round 3
// 97.563 us; speedup vs baseline: 1.7653x; 1.1704x over previous
//
#include <hip/hip_runtime.h>
#include <math.h>

#define HW   128
#define BH   16          // band height (rows per thread)
#define C_CH 256

__device__ __forceinline__ void sig_tanh(float s, float& fg, float& th) {
    float sc = fminf(15.f, fmaxf(-15.f, s));
    float t  = __expf(-sc);                               // e^-s
    fg = __builtin_amdgcn_rcpf(1.f + t);                  // sigmoid
    float t2 = t * t;                                     // e^-2s
    th = (1.f - t2) * __builtin_amdgcn_rcpf(1.f + t2);    // tanh
}

__device__ __forceinline__ float tanh_fast(float s) {
    float sc = fminf(15.f, fmaxf(-15.f, s));
    float t2 = __expf(-2.f * sc);
    return (1.f - t2) * __builtin_amdgcn_rcpf(1.f + t2);
}

// accumulate one stencil row (weights w0,w1,w2) over a 10-wide row {l, a, b, r}
__device__ __forceinline__ void row_acc(float w0, float w1, float w2,
    float l, const float4& a, const float4& b, float r,
    float4& s0, float4& s1)
{
    s0.x = fmaf(w0, l,   fmaf(w1, a.x, fmaf(w2, a.y, s0.x)));
    s0.y = fmaf(w0, a.x, fmaf(w1, a.y, fmaf(w2, a.z, s0.y)));
    s0.z = fmaf(w0, a.y, fmaf(w1, a.z, fmaf(w2, a.w, s0.z)));
    s0.w = fmaf(w0, a.z, fmaf(w1, a.w, fmaf(w2, b.x, s0.w)));
    s1.x = fmaf(w0, a.w, fmaf(w1, b.x, fmaf(w2, b.y, s1.x)));
    s1.y = fmaf(w0, b.x, fmaf(w1, b.y, fmaf(w2, b.z, s1.y)));
    s1.z = fmaf(w0, b.y, fmaf(w1, b.z, fmaf(w2, b.w, s1.z)));
    s1.w = fmaf(w0, b.z, fmaf(w1, b.w, fmaf(w2, r,   s1.w)));
}

__global__ __launch_bounds__(256, 4) void fused_gated_dwconv_reg(
    const float* __restrict__ x, const float* __restrict__ y,
    const float* __restrict__ w, const float* __restrict__ b,
    float* __restrict__ out)
{
    const int tid   = threadIdx.x;
    const int s     = tid & 15;          // col strip (8 cols each)
    const int band  = (tid >> 4) & 7;    // 8 bands of 16 rows
    const int psub  = tid >> 7;          // 2 planes per block
    const int plane = blockIdx.x * 2 + psub;
    const int c     = plane & (C_CH - 1);
    const int rb    = band * BH;
    const int col0  = s * 8;

    const size_t poff = (size_t)plane * (HW * HW);
    const float* yp = y + poff + col0;
    const float* xp = x + poff + col0;
    float*       op = out + poff + col0;

    float wk[9];
    #pragma unroll
    for (int k = 0; k < 9; ++k) wk[k] = w[c * 9 + k];
    const float bias = b[c];

    // rolling 3-row windows (10 wide: left halo, 8 cols, right halo)
    float  yl[3], yr[3];  float4 ya[3], yb[3];
    float  xl[3], xr[3];  float4 xa[3], xb[3];
    float4 fa[2], fb[2];  // f_gate, 2-row window

    #pragma unroll
    for (int t = 0; t < BH + 4; ++t) {
        // ---- load y row (rb-2+t) into slot t%3, with shuffle halo ----
        {
            int gy = rb - 2 + t;
            bool iny = (unsigned)gy < (unsigned)HW;
            const float* p = yp + (size_t)(iny ? gy : 0) * HW;
            float4 a  = *reinterpret_cast<const float4*>(p);
            float4 bb = *reinterpret_cast<const float4*>(p + 4);
            if (!iny) { a = make_float4(0.f,0.f,0.f,0.f); bb = make_float4(0.f,0.f,0.f,0.f); }
            float l = __shfl_up(bb.w, 1, 16);  if (s == 0)  l = 0.f;
            float r = __shfl_down(a.x, 1, 16); if (s == 15) r = 0.f;
            const int sl = t % 3;
            yl[sl] = l; ya[sl] = a; yb[sl] = bb; yr[sl] = r;
        }
        // ---- compute x_stage row (qx = rb-3+t) into slot t%3 ----
        if (t >= 2) {
            int qx = rb - 3 + t;
            bool inx = (unsigned)qx < (unsigned)HW;
            const float* p = xp + (size_t)(inx ? qx : 0) * HW;
            float4 xva = *reinterpret_cast<const float4*>(p);
            float4 xvb = *reinterpret_cast<const float4*>(p + 4);

            const int i0 = (t - 2) % 3, i1 = (t - 1) % 3, i2 = t % 3;
            float4 s0 = make_float4(bias, bias, bias, bias), s1 = s0;
            row_acc(wk[0], wk[1], wk[2], yl[i0], ya[i0], yb[i0], yr[i0], s0, s1);
            row_acc(wk[3], wk[4], wk[5], yl[i1], ya[i1], yb[i1], yr[i1], s0, s1);
            row_acc(wk[6], wk[7], wk[8], yl[i2], ya[i2], yb[i2], yr[i2], s0, s1);

            float4 fga, fgb, tha, thb;
            sig_tanh(s0.x, fga.x, tha.x);
            sig_tanh(s0.y, fga.y, tha.y);
            sig_tanh(s0.z, fga.z, tha.z);
            sig_tanh(s0.w, fga.w, tha.w);
            sig_tanh(s1.x, fgb.x, thb.x);
            sig_tanh(s1.y, fgb.y, thb.y);
            sig_tanh(s1.z, fgb.z, thb.z);
            sig_tanh(s1.w, fgb.w, thb.w);

            float4 xsa, xsb;
            xsa.x = fga.x * (xva.x + tha.x);
            xsa.y = fga.y * (xva.y + tha.y);
            xsa.z = fga.z * (xva.z + tha.z);
            xsa.w = fga.w * (xva.w + tha.w);
            xsb.x = fgb.x * (xvb.x + thb.x);
            xsb.y = fgb.y * (xvb.y + thb.y);
            xsb.z = fgb.z * (xvb.z + thb.z);
            xsb.w = fgb.w * (xvb.w + thb.w);
            if (!inx) { xsa = make_float4(0.f,0.f,0.f,0.f); xsb = make_float4(0.f,0.f,0.f,0.f); }

            float l = __shfl_up(xsb.w, 1, 16);  if (s == 0)  l = 0.f;
            float r = __shfl_down(xsa.x, 1, 16); if (s == 15) r = 0.f;
            xl[i2] = l; xa[i2] = xsa; xb[i2] = xsb; xr[i2] = r;
            fa[t & 1] = fga; fb[t & 1] = fgb;
        }
        // ---- output row r = rb-4+t ----
        if (t >= 4) {
            int r = rb - 4 + t;
            const int i0 = (t - 2) % 3, i1 = (t - 1) % 3, i2 = t % 3;
            float4 s0 = make_float4(bias, bias, bias, bias), s1 = s0;
            row_acc(wk[0], wk[1], wk[2], xl[i0], xa[i0], xb[i0], xr[i0], s0, s1);
            row_acc(wk[3], wk[4], wk[5], xl[i1], xa[i1], xb[i1], xr[i1], s0, s1);
            row_acc(wk[6], wk[7], wk[8], xl[i2], xa[i2], xb[i2], xr[i2], s0, s1);

            const float4 fga = fa[(t + 1) & 1];
            const float4 fgb = fb[(t + 1) & 1];
            const int iy = (t - 2) % 3;   // y row r for the +2y term

            float4 o0, o1;
            o0.x = fmaf(tanh_fast(s0.x), fga.x, 2.f * ya[iy].x);
            o0.y = fmaf(tanh_fast(s0.y), fga.y, 2.f * ya[iy].y);
            o0.z = fmaf(tanh_fast(s0.z), fga.z, 2.f * ya[iy].z);
            o0.w = fmaf(tanh_fast(s0.w), fga.w, 2.f * ya[iy].w);
            o1.x = fmaf(tanh_fast(s1.x), fgb.x, 2.f * yb[iy].x);
            o1.y = fmaf(tanh_fast(s1.y), fgb.y, 2.f * yb[iy].y);
            o1.z = fmaf(tanh_fast(s1.z), fgb.z, 2.f * yb[iy].z);
            o1.w = fmaf(tanh_fast(s1.w), fgb.w, 2.f * yb[iy].w);

            float* po = op + (size_t)r * HW;
            *reinterpret_cast<float4*>(po)     = o0;
            *reinterpret_cast<float4*>(po + 4) = o1;
        }
    }
}

extern "C" void kernel_launch(void* const* d_in, const int* in_sizes, int n_in,
                              void* d_out, int out_size, void* d_ws, size_t ws_size,
                              hipStream_t stream) {
    const float* x = (const float*)d_in[0];
    const float* y = (const float*)d_in[1];
    const float* w = (const float*)d_in[2];
    const float* b = (const float*)d_in[3];
    float* out = (float*)d_out;

    const int planes = in_sizes[0] / (HW * HW);   // B*C = 2048
    dim3 grid(planes / 2);                        // 1024 blocks, 2 planes each
    dim3 block(256);
    fused_gated_dwconv_reg<<<grid, block, 0, stream>>>(x, y, w, b, out);
}